// Round 2
// baseline (491.448 us; speedup 1.0000x reference)
//
#include <hip/hip_runtime.h>

// Problem constants (match reference)
#define BB    32
#define HH    224
#define WW    224
#define OUTC  64
#define KK    5
#define PADP  2
#define LL    (HH * WW)            // 50176; 50176 % 1024 == 0
#define TPOS  4                    // spatial positions per thread (224 % 4 == 0)

__global__ __launch_bounds__(256) void gray_conv_kernel(
    const float* __restrict__ x,     // [B, 1, H, W]
    const float* __restrict__ wgt,   // [OUT, 25]
    float* __restrict__ out)         // [B, OUT, H, W]
{
    // Weights in LDS. Row stride 28 floats = 112 B (16B multiple) so rows are
    // ds_read_b128-aligned. All lanes read the same address -> broadcast, no
    // bank conflicts. Each ds_read now feeds TPOS=4 FMAs (key fix vs round 1:
    // LDS pipe was the bottleneck at 1 read per FMA).
    __shared__ float sw[OUTC][28];
    __shared__ float sw2[OUTC];

    const int tid = threadIdx.x;

    for (int i = tid; i < OUTC * 25; i += 256) {
        sw[i / 25][i % 25] = wgt[i];
    }
    __syncthreads();
    if (tid < OUTC) {
        float s = 0.f;
        #pragma unroll
        for (int d = 0; d < 25; ++d) { float v = sw[tid][d]; s = fmaf(v, v, s); }
        sw2[tid] = s;
    }
    __syncthreads();

    // Each thread: 4 consecutive positions along w. Block covers 1024
    // consecutive positions; L % 1024 == 0 so one block = one batch image.
    const int pos0 = (blockIdx.x * 256 + tid) * TPOS;   // 0 .. B*L-1, mult of 4
    const int b    = pos0 / LL;
    const int rem  = pos0 - b * LL;                     // multiple of 4
    const int h    = rem / WW;
    const int w0   = rem - h * WW;                      // multiple of 4; w0..w0+3 in-row

    const float* xb = x + (size_t)b * LL;

    // 5x8 register patch window covering columns w0-2 .. w0+5, rows h-2 .. h+2.
    // Branchless: clamp address into bounds (always-valid load), mask to 0.
    float pr[KK][KK + TPOS - 1];                        // [5][8]
    #pragma unroll
    for (int ky = 0; ky < KK; ++ky) {
        const int  yy  = h + ky - PADP;
        const int  yc  = min(max(yy, 0), HH - 1);
        const bool oky = (unsigned)yy < (unsigned)HH;
        const float* xr = xb + yc * WW;
        #pragma unroll
        for (int c = 0; c < KK + TPOS - 1; ++c) {
            const int  xxi = w0 + c - PADP;
            const int  xc  = min(max(xxi, 0), WW - 1);
            const bool ok  = oky && ((unsigned)xxi < (unsigned)WW);
            float v = xr[xc];
            pr[ky][c] = ok ? v : 0.f;
        }
    }

    // |x|^2 per position
    float x2[TPOS];
    #pragma unroll
    for (int j = 0; j < TPOS; ++j) {
        float s = 0.f;
        #pragma unroll
        for (int ky = 0; ky < KK; ++ky)
            #pragma unroll
            for (int kx = 0; kx < KK; ++kx) {
                float v = pr[ky][j + kx];
                s = fmaf(v, v, s);
            }
        x2[j] = s;
    }

    float* ob = out + (size_t)b * OUTC * LL + rem;
    #pragma unroll 2
    for (int o = 0; o < OUTC; ++o) {
        float dot[TPOS] = {0.f, 0.f, 0.f, 0.f};
        #pragma unroll
        for (int ky = 0; ky < KK; ++ky) {
            #pragma unroll
            for (int kx = 0; kx < KK; ++kx) {
                const float wv = sw[o][ky * KK + kx];   // LDS broadcast, reused x4
                #pragma unroll
                for (int j = 0; j < TPOS; ++j)
                    dot[j] = fmaf(pr[ky][j + kx], wv, dot[j]);
            }
        }
        const float w2 = sw2[o];
        float4 r;
        {
            float d2;
            d2 = fmaxf(fmaf(-2.f, dot[0], x2[0] + w2), 0.f); r.x = sqrtf(d2);
            d2 = fmaxf(fmaf(-2.f, dot[1], x2[1] + w2), 0.f); r.y = sqrtf(d2);
            d2 = fmaxf(fmaf(-2.f, dot[2], x2[2] + w2), 0.f); r.z = sqrtf(d2);
            d2 = fmaxf(fmaf(-2.f, dot[3], x2[3] + w2), 0.f); r.w = sqrtf(d2);
        }
        *(float4*)(ob + (size_t)o * LL) = r;            // coalesced 1KB/wave store
    }
}

extern "C" void kernel_launch(void* const* d_in, const int* in_sizes, int n_in,
                              void* d_out, int out_size, void* d_ws, size_t ws_size,
                              hipStream_t stream) {
    const float* x   = (const float*)d_in[0];
    const float* wgt = (const float*)d_in[1];
    float* out       = (float*)d_out;

    const int total  = BB * LL;                   // 1,605,632 positions
    const int blocks = total / (256 * TPOS);      // 1568 blocks
    gray_conv_kernel<<<dim3(blocks), dim3(256), 0, stream>>>(x, wgt, out);
}